// Round 9
// baseline (1007.472 us; speedup 1.0000x reference)
//
#include <hip/hip_runtime.h>
#include <math.h>

#define B_   64
#define T_   2048
#define HID_ 128
#define G3_  384   // 3*HID
#define IN_  128
#define E_   64

#define TS_  128   // t-tile of gi GEMM block

typedef _Float16 h2f  __attribute__((ext_vector_type(2)));
typedef _Float16 f16x8 __attribute__((ext_vector_type(8)));
typedef float    f32x4 __attribute__((ext_vector_type(4)));

__device__ __forceinline__ float rcp_(float x)     { return __builtin_amdgcn_rcpf(x); }
__device__ __forceinline__ float sigmoid_(float x) { return rcp_(1.f + __expf(-x)); }
__device__ __forceinline__ float tanh_(float x)    { return 1.f - 2.f * rcp_(1.f + __expf(2.f * x)); }

// pack 8 f32 -> f16x8 via 4x cvt_pkrtz
__device__ __forceinline__ f16x8 pack8_(float4 a, float4 b) {
    uint4 u;
    u.x = __builtin_bit_cast(unsigned, __builtin_amdgcn_cvt_pkrtz(a.x, a.y));
    u.y = __builtin_bit_cast(unsigned, __builtin_amdgcn_cvt_pkrtz(a.z, a.w));
    u.z = __builtin_bit_cast(unsigned, __builtin_amdgcn_cvt_pkrtz(b.x, b.y));
    u.w = __builtin_bit_cast(unsigned, __builtin_amdgcn_cvt_pkrtz(b.z, b.w));
    return __builtin_bit_cast(f16x8, u);
}

// ---------------------------------------------------------------------------
// gi GEMM v3, f16 MFMA, register-blocked like rec_kernel:
//   gi[tl][b][g] = x[b][t0+tl][:] . w_ih[g][:] + bias[g]
// Block = (128 t-rows) x (all 384 g) for one b; 256 threads.
// Wave w owns N-tiles nt = 6w..6w+5: w_ih B-frags packed ONCE into 24 f16x8
// regs (the round-8 gi version re-streamed these 8x from global -- that was
// the 189us). A-frags (x rows) loaded per k-chunk: 8 M-tiles x 2 dwordx4;
// 48 independent MFMAs per kc hide the next chunk's loads.
// acc 8x6 f32x4 = 192 accumulators -> AGPR side of unified file.
// Matrix cost ~5us chip-wide; HBM write floor ~32us dominates.
// ---------------------------------------------------------------------------
__global__ __launch_bounds__(256, 1)
void gi_gemm(const float* __restrict__ x, const float* __restrict__ w_ih,
             const float* __restrict__ b_ih, const float* __restrict__ b_hh,
             float* __restrict__ gi, int t0)
{
    const int tid = threadIdx.x;
    const int w   = tid >> 6;          // wave 0..3 -> N-tiles 6w..6w+5
    const int l   = tid & 63;
    const int ln  = l & 15;
    const int kq  = l >> 4;
    const int tt  = blockIdx.x;        // t-tile (128 rows) within chunk
    const int b   = blockIdx.y;

    // B-frags + bias, loaded once
    f16x8 wfr[6][4];
    float bias[6];
    #pragma unroll
    for (int i = 0; i < 6; i++) {
        const int col = (6 * w + i) * 16 + ln;
        const float* wr = w_ih + (size_t)col * IN_;
        #pragma unroll
        for (int kc = 0; kc < 4; kc++) {
            const float* p = wr + kc * 32 + kq * 8;
            float4 q0 = *reinterpret_cast<const float4*>(p);
            float4 q1 = *reinterpret_cast<const float4*>(p + 4);
            wfr[i][kc] = pack8_(q0, q1);
        }
        bias[i] = b_ih[col] + (col < 256 ? b_hh[col] : 0.f);
    }

    f32x4 acc[8][6];
    #pragma unroll
    for (int mt = 0; mt < 8; mt++)
        #pragma unroll
        for (int i = 0; i < 6; i++)
            acc[mt][i] = (f32x4){0.f, 0.f, 0.f, 0.f};

    const float* xb = x + ((size_t)b * T_ + (size_t)(t0 + tt * TS_)) * IN_;

    #pragma unroll
    for (int kc = 0; kc < 4; kc++) {
        const int ko = kc * 32 + kq * 8;
        f16x8 afr[8];
        #pragma unroll
        for (int mt = 0; mt < 8; mt++) {
            const float* xr = xb + (size_t)(mt * 16 + ln) * IN_ + ko;
            float4 p0 = *reinterpret_cast<const float4*>(xr);
            float4 p1 = *reinterpret_cast<const float4*>(xr + 4);
            afr[mt] = pack8_(p0, p1);
        }
        #pragma unroll
        for (int i = 0; i < 6; i++)
            #pragma unroll
            for (int mt = 0; mt < 8; mt++)
                acc[mt][i] = __builtin_amdgcn_mfma_f32_16x16x32_f16(afr[mt], wfr[i][kc],
                                                                   acc[mt][i], 0, 0, 0);
    }

    // store: C row = kq*4 + r (t-dim within M-tile), col = ln (g-dim)
    #pragma unroll
    for (int mt = 0; mt < 8; mt++) {
        #pragma unroll
        for (int r = 0; r < 4; r++) {
            const size_t trow = (size_t)(tt * TS_ + mt * 16 + kq * 4 + r);
            float* go = gi + trow * (B_ * G3_) + (size_t)b * G3_ + (size_t)(6 * w) * 16 + ln;
            #pragma unroll
            for (int i = 0; i < 6; i++)
                go[i * 16] = acc[mt][i][r] + bias[i];
        }
    }
}

// ---------------------------------------------------------------------------
// GRU recurrence, MFMA core with replicated-A trick (UNCHANGED from round 8).
// ---------------------------------------------------------------------------
#define REC_STEP(CUR, LD, TLOAD, PB)                                           \
  {                                                                            \
    const float* gp_ = gib + (size_t)(TLOAD) * S;                              \
    LD[0] = gp_[c0];       LD[1] = gp_[c0 + 64];                               \
    LD[2] = gp_[c0 + 128]; LD[3] = gp_[c0 + 192];                              \
    LD[4] = gp_[c0 + 256]; LD[5] = gp_[c0 + 320];                              \
    const char* hb_ = (const char*)(&h2_sh[PB][0]) + kq * 16;                  \
    f16x8 af_[4];                                                              \
    af_[0] = __builtin_bit_cast(f16x8, *(const uint4*)(hb_));                  \
    af_[1] = __builtin_bit_cast(f16x8, *(const uint4*)(hb_ + 64));             \
    af_[2] = __builtin_bit_cast(f16x8, *(const uint4*)(hb_ + 128));            \
    af_[3] = __builtin_bit_cast(f16x8, *(const uint4*)(hb_ + 192));            \
    f32x4 ac_[6];                                                              \
    _Pragma("unroll")                                                          \
    for (int m = 0; m < 6; m++) ac_[m] = (f32x4){0.f, 0.f, 0.f, 0.f};          \
    _Pragma("unroll")                                                          \
    for (int kc = 0; kc < 4; kc++) {                                           \
      _Pragma("unroll")                                                        \
      for (int m = 0; m < 6; m++)                                              \
        ac_[m] = __builtin_amdgcn_mfma_f32_16x16x32_f16(af_[kc], wfr[m][kc],   \
                                                        ac_[m], 0, 0, 0);      \
    }                                                                          \
    const float r0 = sigmoid_(CUR[0] + ac_[0][0]);                             \
    const float r1 = sigmoid_(CUR[1] + ac_[1][0]);                             \
    const float z0 = sigmoid_(CUR[2] + ac_[2][0]);                             \
    const float z1 = sigmoid_(CUR[3] + ac_[3][0]);                             \
    const float n0 = tanh_(CUR[4] + r0 * (ac_[4][0] + bh0));                   \
    const float n1 = tanh_(CUR[5] + r1 * (ac_[5][0] + bh1));                   \
    hj0 = (1.f - z0) * n0 + z0 * hj0;                                          \
    hj1 = (1.f - z1) * n1 + z1 * hj1;                                          \
    hs0 += hj0; hs1 += hj1;                                                    \
    if (kq == 0) {                                                             \
      h2_sh[(PB) ^ 1][c0] = (_Float16)hj0;                                     \
      h2_sh[(PB) ^ 1][c1] = (_Float16)hj1;                                     \
    }                                                                          \
    __syncthreads();                                                           \
  }

__global__ __launch_bounds__(256, 1)
void rec_kernel(const float* __restrict__ gi, const float* __restrict__ w_hh,
                const float* __restrict__ b_hh,
                const float* __restrict__ w_proj, const float* __restrict__ b_proj,
                float* __restrict__ out, float* __restrict__ state,
                int t0, int t1)
{
    const int tid  = threadIdx.x;
    const int b    = blockIdx.x;
    const int w    = tid >> 6;     // wave 0..3
    const int lane = tid & 63;
    const int ln   = lane & 15;
    const int kq   = lane >> 4;
    const int c0   = 16 * w + ln;  // h-col family 0 (family 1 = c0+64)
    const int c1   = c0 + 64;
    const int nT   = t1 - t0;      // multiple of 128 -> multiple of 4

    __shared__ _Float16 h2_sh[2][HID_];   // h as f16, double-buffered
    __shared__ float pooled[HID_];

    // B-frags: wfr[m][kc] = packed w_hh[c0+64m][kc*32+kq*8 .. +8)
    f16x8 wfr[6][4];
    #pragma unroll
    for (int m = 0; m < 6; m++) {
        const float* wr = w_hh + (size_t)(c0 + 64 * m) * HID_;
        #pragma unroll
        for (int kc = 0; kc < 4; kc++) {
            const float* p = wr + kc * 32 + kq * 8;
            float4 q0 = *reinterpret_cast<const float4*>(p);
            float4 q1 = *reinterpret_cast<const float4*>(p + 4);
            wfr[m][kc] = pack8_(q0, q1);
        }
    }
    const float bh0 = b_hh[256 + c0];
    const float bh1 = b_hh[256 + c1];

    float hj0, hj1, hs0, hs1;
    if (t0 == 0) { hj0 = hj1 = hs0 = hs1 = 0.f; }
    else {
        hj0 = state[b * HID_ + c0];             hj1 = state[b * HID_ + c1];
        hs0 = state[B_ * HID_ + b * HID_ + c0]; hs1 = state[B_ * HID_ + b * HID_ + c1];
    }
    if (kq == 0) {
        h2_sh[0][c0] = (_Float16)hj0;
        h2_sh[0][c1] = (_Float16)hj1;
    }
    __syncthreads();

    const float* gib = gi + (size_t)b * G3_;
    const size_t S = (size_t)B_ * G3_;

    // ring-4 gi buffers; prefetch depth 2
    float g0[6], g1[6], g2[6], g3[6];
    {
        const float* p0 = gib;
        const float* p1 = gib + S;
        g0[0]=p0[c0]; g0[1]=p0[c0+64]; g0[2]=p0[c0+128]; g0[3]=p0[c0+192]; g0[4]=p0[c0+256]; g0[5]=p0[c0+320];
        g1[0]=p1[c0]; g1[1]=p1[c0+64]; g1[2]=p1[c0+128]; g1[3]=p1[c0+192]; g1[4]=p1[c0+256]; g1[5]=p1[c0+320];
    }

    int pb = 0;
    for (int t = 0; t < nT; t += 4) {
        const int nTm1 = nT - 1;
        int t2 = t + 2 < nTm1 ? t + 2 : nTm1;
        int t3 = t + 3 < nTm1 ? t + 3 : nTm1;
        int t4 = t + 4 < nTm1 ? t + 4 : nTm1;
        int t5 = t + 5 < nTm1 ? t + 5 : nTm1;
        REC_STEP(g0, g2, t2, pb); pb ^= 1;
        REC_STEP(g1, g3, t3, pb); pb ^= 1;
        REC_STEP(g2, g0, t4, pb); pb ^= 1;
        REC_STEP(g3, g1, t5, pb); pb ^= 1;
    }

    if (t1 < T_) {
        if (kq == 0) {
            state[b * HID_ + c0]             = hj0;  state[b * HID_ + c1]             = hj1;
            state[B_ * HID_ + b * HID_ + c0] = hs0;  state[B_ * HID_ + b * HID_ + c1] = hs1;
        }
    } else {
        if (kq == 0) {
            pooled[c0] = hs0 * (1.f / (float)T_);
            pooled[c1] = hs1 * (1.f / (float)T_);
        }
        __syncthreads();
        if (tid < E_) {
            const float4* wpj = reinterpret_cast<const float4*>(w_proj + (size_t)tid * HID_);
            const float4* pp  = reinterpret_cast<const float4*>(pooled);
            float a0 = 0.f, a1 = 0.f, a2 = 0.f, a3 = 0.f;
            #pragma unroll
            for (int k = 0; k < 32; k++) {
                float4 wv = wpj[k]; float4 pv = pp[k];
                a0 = fmaf(wv.x, pv.x, a0);
                a1 = fmaf(wv.y, pv.y, a1);
                a2 = fmaf(wv.z, pv.z, a2);
                a3 = fmaf(wv.w, pv.w, a3);
            }
            out[b * E_ + tid] = (a0 + a1) + (a2 + a3) + b_proj[tid];
        }
    }
}

extern "C" void kernel_launch(void* const* d_in, const int* in_sizes, int n_in,
                              void* d_out, int out_size, void* d_ws, size_t ws_size,
                              hipStream_t stream)
{
    const float* x      = (const float*)d_in[0];
    const float* w_ih   = (const float*)d_in[1];
    const float* w_hh   = (const float*)d_in[2];
    const float* b_ih   = (const float*)d_in[3];
    const float* b_hh   = (const float*)d_in[4];
    const float* w_proj = (const float*)d_in[5];
    const float* b_proj = (const float*)d_in[6];
    float* out = (float*)d_out;

    // ws layout: [ gi chunk buffer: chunkT * B * 3H * f32 ][ state: h + hsum ]
    const size_t state_bytes = (size_t)2 * B_ * HID_ * sizeof(float);
    const size_t per_t = (size_t)B_ * G3_ * sizeof(float);
    size_t avail = ws_size > state_bytes ? ws_size - state_bytes : 0;
    int chunkT = (int)(avail / per_t);
    if (chunkT > T_) chunkT = T_;
    chunkT &= ~(TS_ - 1);
    if (chunkT < TS_) chunkT = TS_;

    float* gi_buf = (float*)d_ws;
    float* state  = (float*)((char*)d_ws + (size_t)chunkT * per_t);

    for (int t0 = 0; t0 < T_; t0 += chunkT) {
        int t1 = t0 + chunkT; if (t1 > T_) t1 = T_;
        int nT = t1 - t0;
        gi_gemm<<<dim3(nT / TS_, B_), dim3(256), 0, stream>>>(x, w_ih, b_ih, b_hh, gi_buf, t0);
        rec_kernel<<<dim3(B_), dim3(256), 0, stream>>>(gi_buf, w_hh, b_hh, w_proj, b_proj,
                                                       out, state, t0, t1);
    }
}